// Round 4
// baseline (524.275 us; speedup 1.0000x reference)
//
#include <hip/hip_runtime.h>
#include <hip/hip_bf16.h>

// R7: base = R4 structure (32x32x16 split-bf16, global_load_lds width=16,
// both-sides XOR swizzle, operand order (code, act) -> float4 stores with
// per-lane row constants — R5's swap was a measured regression, reverted).
// NEW: (1) XCD-aware bijective block remap: 1D grid 2048, y = yg*8 + (fid&7)
// so all 16 row-group blocks sharing a B column-slice run on ONE XCD ->
// B fetched from HBM once (16.4 MB) instead of 16x (262 MB refetch measured:
// FETCH_SIZE=307MB). (2) launch_bounds(256,4) (VGPR 84 fits) for latency
// hiding. Epilogue keeps R5's cheap math (log2-artanh, raw v_sqrt).

typedef __attribute__((ext_vector_type(8))) short short8;
typedef __attribute__((ext_vector_type(16))) float f32x16;
typedef unsigned short u16;
typedef unsigned int u32;

__device__ inline float bits2f(unsigned u){ union{unsigned u; float f;} x; x.u=u; return x.f; }
__device__ inline u16 f2bf(float f){
  union { float f; unsigned u; } x; x.f = f;
  unsigned r = x.u + 0x7fff + ((x.u >> 16) & 1);   // round-to-nearest-even
  return (u16)(r >> 16);
}
__device__ inline void bfsplit(float f, u16 &h, u16 &l){
  u16 hb = f2bf(f);
  float hf = bits2f(((unsigned)hb) << 16);
  h = hb;
  l = f2bf(f - hf);
}

__device__ inline float wred(float x){
#pragma unroll
  for (int off = 32; off; off >>= 1) x += __shfl_xor(x, off, 64);
  return x;
}
__device__ inline float wred32(float x){
#pragma unroll
  for (int off = 16; off; off >>= 1) x += __shfl_xor(x, off, 64);
  return x;
}

__device__ inline float dotW(const float* __restrict__ w, const float* __restrict__ p){
  float m = 0.f;
#pragma unroll
  for (int i = 0; i < 32; ++i){
    float4 u = *(const float4*)(w + 4*i);
    const float* q = p + 4*i;
    m = fmaf(u.x, q[0], m); m = fmaf(u.y, q[1], m);
    m = fmaf(u.z, q[2], m); m = fmaf(u.w, q[3], m);
  }
  return m;
}

// async global->LDS, 16B per lane; dest = wave-uniform base + lane*16
__device__ inline void gl_lds16(const u16* g, u16* l){
  __builtin_amdgcn_global_load_lds(
      (const __attribute__((address_space(1))) u32*)g,
      (__attribute__((address_space(3))) u32*)l, 16, 0, 0);
}

// ---------------- Kernel 1: per-row hyperbolic MLP chain (f32) ----------------
__global__ __launch_bounds__(64) void prep_kernel(
    const float* __restrict__ vt, const float* __restrict__ Wm,
    const float* __restrict__ bias,
    u16* __restrict__ ahi, u16* __restrict__ alo, float* __restrict__ x2o)
{
  const int row = blockIdx.x, lane = threadIdx.x;
  const int e0 = 2*lane;
  const float CLIP = 0.99999f;  // 1 - 1e-5

  float v0 = vt[row*128 + e0];
  float v1 = vt[row*128 + e0 + 1];
  float n1 = fmaxf(sqrtf(wred(v0*v0 + v1*v1)), 1e-15f);
  float s1 = tanhf(n1)/n1;
  float p0 = s1*v0, p1 = s1*v1;
  __shared__ float sP[128];
  sP[e0] = p0; sP[e0+1] = p1;
  __syncthreads();
  float xn = fmaxf(sqrtf(wred(p0*p0 + p1*p1)), 1e-15f);
  float mx0 = dotW(Wm + e0*128, sP);
  float mx1 = dotW(Wm + (e0+1)*128, sP);
  float Mxn = fmaxf(sqrtf(wred(mx0*mx0 + mx1*mx1)), 1e-15f);
  float smv = tanhf((Mxn/xn) * atanhf(fminf(xn, CLIP))) / Mxn;
  float m0 = smv*mx0, m1 = smv*mx1;
  float b0 = bias[e0], b1 = bias[e0+1];
  float nb = fmaxf(sqrtf(wred(b0*b0 + b1*b1)), 1e-15f);
  float sb = tanhf(nb)/nb;
  float eb0 = sb*b0, eb1 = sb*b1;
  float x2m = wred(m0*m0 + m1*m1);
  float y2e = wred(eb0*eb0 + eb1*eb1);
  float xy  = wred(m0*eb0 + m1*eb1);
  float ca = 1.f + 2.f*xy + y2e;
  float cb = 1.f - x2m;
  float den = fmaxf(1.f + 2.f*xy + x2m*y2e, 1e-15f);
  float q0 = (ca*m0 + cb*eb0)/den, q1 = (ca*m1 + cb*eb1)/den;
  float n2 = fmaxf(sqrtf(wred(q0*q0 + q1*q1)), 1e-15f);
  float u = atanhf(fminf(n2, CLIP));
  float sv = u/n2;
  float w0v = sv*q0, w1v = sv*q1;
  float n3 = fmaxf(sqrtf(wred(w0v*w0v + w1v*w1v)), 1e-15f);
  float s3 = tanhf(n3)/n3;
  float P0 = s3*w0v, P1 = s3*w1v;
  float x2v = wred(P0*P0 + P1*P1);
  u16 h0, l0, h1, l1;
  bfsplit(P0, h0, l0); bfsplit(P1, h1, l1);
  ahi[row*128 + e0] = h0; ahi[row*128 + e0 + 1] = h1;
  alo[row*128 + e0] = l0; alo[row*128 + e0 + 1] = l1;
  if (lane == 0) x2o[row] = x2v;
}

// ------- Kernel 2: split code -> Bh/Bl (bf16) + y2 (one pass over code) -------
__global__ __launch_bounds__(256) void split_y2_kernel(
    const float* __restrict__ code, u16* __restrict__ Bh,
    u16* __restrict__ Bl, float* __restrict__ y2o)
{
  const int c = threadIdx.x & 31, r = threadIdx.x >> 5;
  const int row = blockIdx.x*8 + r;
  float4 u = *(const float4*)(code + (size_t)row*128 + c*4);
  u16 h0,h1,h2,h3,l0,l1,l2,l3;
  bfsplit(u.x,h0,l0); bfsplit(u.y,h1,l1);
  bfsplit(u.z,h2,l2); bfsplit(u.w,h3,l3);
  ushort4 hv; hv.x=h0; hv.y=h1; hv.z=h2; hv.w=h3;
  ushort4 lv; lv.x=l0; lv.y=l1; lv.z=l2; lv.w=l3;
  *(ushort4*)(Bh + (size_t)row*128 + c*4) = hv;
  *(ushort4*)(Bl + (size_t)row*128 + c*4) = lv;
  float s = fmaf(u.x,u.x, fmaf(u.y,u.y, fmaf(u.z,u.z, u.w*u.w)));
  s = wred32(s);
  if (c == 0) y2o[row] = s;
}

// ------- Kernel 3: 32x32x16 split-bf16 GEMM + fused hyperbolic-dist epilogue ----
// 1D grid 2048, XCD remap: xcd = fid&7, li = fid>>3, yg = li>>4, xi = li&15;
// column-block y = yg*8 + xcd (exit if >=125), row-block = xi.
// Per XCD: y-groups processed sequentially, 16 row-blocks each -> B slice
// (131 KB) stays in that XCD's L2; B HBM fetch = 16.4 MB total.
// Block: 4 waves; 128 rows (32/wave, A persistent), 4 rounds x 64 cols.
// MFMA operands (code, act): D reg = code col, D lane = act row -> float4
// stores (per-lane row constants, per-reg col constants).
__global__ __launch_bounds__(256, 4) void decode_main(
    const u16* __restrict__ Bh_g, const u16* __restrict__ Bl_g,
    const u16* __restrict__ ahi_g, const u16* __restrict__ alo_g,
    const float* __restrict__ x2g, const float* __restrict__ y2g,
    const float* __restrict__ fbg, const float* __restrict__ tempg,
    float* __restrict__ outp)
{
  __shared__ __align__(16) u16 sBh[64*128];   // 16 KB
  __shared__ __align__(16) u16 sBl[64*128];   // 16 KB
  const int fid = blockIdx.x;
  const int xcd = fid & 7, li = fid >> 3;
  const int yg  = li >> 4, xi = li & 15;
  const int ycb = yg*8 + xcd;                 // column-block 0..127
  if (ycb >= 125) return;                     // 48 pad blocks exit
  const int n_base = ycb*256;

  const int tid  = threadIdx.x;
  const int wave = tid >> 6, lane = tid & 63;
  const int l32  = lane & 31, half = lane >> 5;
  const int m0   = xi*128 + wave*32;
  const int arow = m0 + l32;

  // Persistent A fragments (act): operand layout [n=lane&31][k = ks*16+half*8+j]
  short8 ah[8], al[8];
#pragma unroll
  for (int ks = 0; ks < 8; ++ks){
    ah[ks] = *(const short8*)(ahi_g + (size_t)arow*128 + ks*16 + half*8);
    al[ks] = *(const short8*)(alo_g + (size_t)arow*128 + ks*16 + half*8);
  }
  // Per-row (per-lane) scalar precomputes
  const float xv  = x2g[arow];
  const float bb  = 1.f - xv;
  const float ntb = -2.f*bb;
  const float b2  = bb*bb;
  const float tmp = tempg[0];
  const float nit2 = -0.4804530139182014f/(tmp*tmp);  // -(ln2)^2/t^2 (log2 form)

  // staging geometry (per-thread, round-invariant)
  int s_col[4], s_swz[4], s_ldb[4];
#pragma unroll
  for (int it = 0; it < 4; ++it){
    int id = it*256 + tid;
    s_col[it] = id >> 4;
    int sg = id & 15;
    s_swz[it] = ((sg*16) ^ ((s_col[it] & 7) << 4)) >> 1;     // u16 units
    s_ldb[it] = (it*256 + (tid & ~63)) * 8;                  // wave-uniform, u16 units
  }

  for (int rnd = 0; rnd < 4; ++rnd){
    const int n0r = n_base + rnd*64;
    __syncthreads();                 // LDS reuse fence (prev round's reads done)
#pragma unroll
    for (int it = 0; it < 4; ++it){
      size_t gb = (size_t)(n0r + s_col[it])*128 + s_swz[it];
      gl_lds16(Bh_g + gb, &sBh[s_ldb[it]]);
    }
#pragma unroll
    for (int it = 0; it < 4; ++it){
      size_t gb = (size_t)(n0r + s_col[it])*128 + s_swz[it];
      gl_lds16(Bl_g + gb, &sBl[s_ldb[it]]);
    }
    __syncthreads();                 // compiler drains vmcnt before barrier

#pragma unroll
    for (int ct = 0; ct < 2; ++ct){
      const int ccol = ct*32 + l32;  // code col = lane&31 (M-operand lane idx)
      f32x16 acch = {0.f,0.f,0.f,0.f,0.f,0.f,0.f,0.f,0.f,0.f,0.f,0.f,0.f,0.f,0.f,0.f};
      f32x16 accx = {0.f,0.f,0.f,0.f,0.f,0.f,0.f,0.f,0.f,0.f,0.f,0.f,0.f,0.f,0.f,0.f};
#pragma unroll
      for (int ks = 0; ks < 8; ++ks){
        int kb  = ks*32 + half*16;                           // byte within row
        int off = (ccol*256 + (kb ^ ((ccol & 7) << 4))) >> 1; // u16 idx, swizzled
        short8 bh = *(const short8*)(&sBh[off]);
        short8 bl = *(const short8*)(&sBl[off]);
        acch = __builtin_amdgcn_mfma_f32_32x32x16_bf16(bh, ah[ks], acch, 0, 0, 0);
        accx = __builtin_amdgcn_mfma_f32_32x32x16_bf16(bl, ah[ks], accx, 0, 0, 0);
        accx = __builtin_amdgcn_mfma_f32_32x32x16_bf16(bh, al[ks], accx, 0, 0, 0);
      }
      // D: code col (reg r) = (r&3)+8*(r>>2)+4*half, act row = lane&31.
      const int cb = n0r + ct*32 + half*4;
#pragma unroll
      for (int g = 0; g < 4; ++g){
        const int cg = cb + g*8;
        const float4 y2v4 = *(const float4*)(y2g + cg);
        const float4 fbv4 = *(const float4*)(fbg + cg);
        float4 o;
#pragma unroll
        for (int q = 0; q < 4; ++q){
          const int r = g*4 + q;
          float y2v = ((const float*)&y2v4)[q];
          float t   = acch[r] + accx[r];        // xy, f32-accurate
          float two = t + t;
          float a   = (1.f + y2v) - two;        // 1 - 2xy + y2
          float den = fmaf(xv, y2v, 1.f - two);
          float dc  = fmaxf(den, 1e-15f);
          float num2 = fmaf(a*xv, a, fmaf(ntb*t, a, b2*y2v));
          float sq  = __builtin_amdgcn_sqrtf(fmaxf(num2, 0.f));
          float s   = fminf(sq, 0.99999f*dc);   // norm clip at 1-1e-5
          float lg  = __log2f(__fdividef(dc + s, dc - s)); // 2*artanh via log2
          ((float*)&o)[q] = fmaf(lg*lg, nit2, ((const float*)&fbv4)[q]);
        }
        *(float4*)(outp + (size_t)arow*32000 + cg) = o;
      }
    }
  }
}

extern "C" void kernel_launch(void* const* d_in, const int* in_sizes, int n_in,
                              void* d_out, int out_size, void* d_ws, size_t ws_size,
                              hipStream_t stream) {
  const float* vt   = (const float*)d_in[0];  // v_tangent [16,128,128]
  const float* code = (const float*)d_in[1];  // code_points [32000,128]
  const float* Wm   = (const float*)d_in[2];  // W [128,128]
  const float* bias = (const float*)d_in[3];  // b [128]
  const float* fb   = (const float*)d_in[4];  // freq_bias [32000]
  const float* temp = (const float*)d_in[5];  // temperature [1]
  float* outp = (float*)d_out;

  char* ws = (char*)d_ws;
  u16*   ahi = (u16*)ws;                            // 512 KB
  u16*   alo = (u16*)(ws + 512*1024);               // 512 KB
  float* x2  = (float*)(ws + 1024*1024);            // 8 KB
  float* y2  = (float*)(ws + 1024*1024 + 8192);     // 128 KB
  u16*   Bh  = (u16*)(ws + 1280*1024);              // 8.192 MB
  u16*   Bl  = (u16*)(ws + 1280*1024 + 8192*1024);  // 8.192 MB

  prep_kernel<<<2048, 64, 0, stream>>>(vt, Wm, bias, ahi, alo, x2);
  split_y2_kernel<<<4000, 256, 0, stream>>>(code, Bh, Bl, y2);
  decode_main<<<2048, 256, 0, stream>>>(Bh, Bl, ahi, alo, x2, y2, fb, temp, outp);
}

// Round 5
// 410.111 us; speedup vs baseline: 1.2784x; 1.2784x over previous
//
#include <hip/hip_runtime.h>
#include <hip/hip_bf16.h>

// R8: fix R7's two confounds and add the real lever.
// (1) REVERT launch_bounds(256,4) -> (256,2): R7 forced VGPR 84->64, causing
//     scratch spills (WRITE_SIZE 378->525MB measured). LDS=64KB limits to
//     2 blocks/CU anyway; give the allocator room.
// (2) KEEP XCD remap (FETCH 307->209MB measured).
// (3) NEW: T3 2-phase pipeline — double-buffered 32KB B-tile, STAGE(next)
//     issued BEFORE compute(cur), ONE barrier per round. The vmcnt(0) drain
//     at the barrier now lands after ~1.5k cycles of MFMA+epilogue, hiding
//     the global_load_lds latency that had decode 64% idle (MfmaUtil 8.5%,
//     VALUBusy 27%).

typedef __attribute__((ext_vector_type(8))) short short8;
typedef __attribute__((ext_vector_type(16))) float f32x16;
typedef unsigned short u16;
typedef unsigned int u32;

__device__ inline float bits2f(unsigned u){ union{unsigned u; float f;} x; x.u=u; return x.f; }
__device__ inline u16 f2bf(float f){
  union { float f; unsigned u; } x; x.f = f;
  unsigned r = x.u + 0x7fff + ((x.u >> 16) & 1);   // round-to-nearest-even
  return (u16)(r >> 16);
}
__device__ inline void bfsplit(float f, u16 &h, u16 &l){
  u16 hb = f2bf(f);
  float hf = bits2f(((unsigned)hb) << 16);
  h = hb;
  l = f2bf(f - hf);
}

__device__ inline float wred(float x){
#pragma unroll
  for (int off = 32; off; off >>= 1) x += __shfl_xor(x, off, 64);
  return x;
}
__device__ inline float wred32(float x){
#pragma unroll
  for (int off = 16; off; off >>= 1) x += __shfl_xor(x, off, 64);
  return x;
}

__device__ inline float dotW(const float* __restrict__ w, const float* __restrict__ p){
  float m = 0.f;
#pragma unroll
  for (int i = 0; i < 32; ++i){
    float4 u = *(const float4*)(w + 4*i);
    const float* q = p + 4*i;
    m = fmaf(u.x, q[0], m); m = fmaf(u.y, q[1], m);
    m = fmaf(u.z, q[2], m); m = fmaf(u.w, q[3], m);
  }
  return m;
}

// async global->LDS, 16B per lane; dest = wave-uniform base + lane*16
__device__ inline void gl_lds16(const u16* g, u16* l){
  __builtin_amdgcn_global_load_lds(
      (const __attribute__((address_space(1))) u32*)g,
      (__attribute__((address_space(3))) u32*)l, 16, 0, 0);
}

// ---------------- Kernel 1: per-row hyperbolic MLP chain (f32) ----------------
__global__ __launch_bounds__(64) void prep_kernel(
    const float* __restrict__ vt, const float* __restrict__ Wm,
    const float* __restrict__ bias,
    u16* __restrict__ ahi, u16* __restrict__ alo, float* __restrict__ x2o)
{
  const int row = blockIdx.x, lane = threadIdx.x;
  const int e0 = 2*lane;
  const float CLIP = 0.99999f;  // 1 - 1e-5

  float v0 = vt[row*128 + e0];
  float v1 = vt[row*128 + e0 + 1];
  float n1 = fmaxf(sqrtf(wred(v0*v0 + v1*v1)), 1e-15f);
  float s1 = tanhf(n1)/n1;
  float p0 = s1*v0, p1 = s1*v1;
  __shared__ float sP[128];
  sP[e0] = p0; sP[e0+1] = p1;
  __syncthreads();
  float xn = fmaxf(sqrtf(wred(p0*p0 + p1*p1)), 1e-15f);
  float mx0 = dotW(Wm + e0*128, sP);
  float mx1 = dotW(Wm + (e0+1)*128, sP);
  float Mxn = fmaxf(sqrtf(wred(mx0*mx0 + mx1*mx1)), 1e-15f);
  float smv = tanhf((Mxn/xn) * atanhf(fminf(xn, CLIP))) / Mxn;
  float m0 = smv*mx0, m1 = smv*mx1;
  float b0 = bias[e0], b1 = bias[e0+1];
  float nb = fmaxf(sqrtf(wred(b0*b0 + b1*b1)), 1e-15f);
  float sb = tanhf(nb)/nb;
  float eb0 = sb*b0, eb1 = sb*b1;
  float x2m = wred(m0*m0 + m1*m1);
  float y2e = wred(eb0*eb0 + eb1*eb1);
  float xy  = wred(m0*eb0 + m1*eb1);
  float ca = 1.f + 2.f*xy + y2e;
  float cb = 1.f - x2m;
  float den = fmaxf(1.f + 2.f*xy + x2m*y2e, 1e-15f);
  float q0 = (ca*m0 + cb*eb0)/den, q1 = (ca*m1 + cb*eb1)/den;
  float n2 = fmaxf(sqrtf(wred(q0*q0 + q1*q1)), 1e-15f);
  float u = atanhf(fminf(n2, CLIP));
  float sv = u/n2;
  float w0v = sv*q0, w1v = sv*q1;
  float n3 = fmaxf(sqrtf(wred(w0v*w0v + w1v*w1v)), 1e-15f);
  float s3 = tanhf(n3)/n3;
  float P0 = s3*w0v, P1 = s3*w1v;
  float x2v = wred(P0*P0 + P1*P1);
  u16 h0, l0, h1, l1;
  bfsplit(P0, h0, l0); bfsplit(P1, h1, l1);
  ahi[row*128 + e0] = h0; ahi[row*128 + e0 + 1] = h1;
  alo[row*128 + e0] = l0; alo[row*128 + e0 + 1] = l1;
  if (lane == 0) x2o[row] = x2v;
}

// ------- Kernel 2: split code -> Bh/Bl (bf16) + y2 (one pass over code) -------
__global__ __launch_bounds__(256) void split_y2_kernel(
    const float* __restrict__ code, u16* __restrict__ Bh,
    u16* __restrict__ Bl, float* __restrict__ y2o)
{
  const int c = threadIdx.x & 31, r = threadIdx.x >> 5;
  const int row = blockIdx.x*8 + r;
  float4 u = *(const float4*)(code + (size_t)row*128 + c*4);
  u16 h0,h1,h2,h3,l0,l1,l2,l3;
  bfsplit(u.x,h0,l0); bfsplit(u.y,h1,l1);
  bfsplit(u.z,h2,l2); bfsplit(u.w,h3,l3);
  ushort4 hv; hv.x=h0; hv.y=h1; hv.z=h2; hv.w=h3;
  ushort4 lv; lv.x=l0; lv.y=l1; lv.z=l2; lv.w=l3;
  *(ushort4*)(Bh + (size_t)row*128 + c*4) = hv;
  *(ushort4*)(Bl + (size_t)row*128 + c*4) = lv;
  float s = fmaf(u.x,u.x, fmaf(u.y,u.y, fmaf(u.z,u.z, u.w*u.w)));
  s = wred32(s);
  if (c == 0) y2o[row] = s;
}

// ------- Kernel 3: 32x32x16 split-bf16 GEMM + fused hyperbolic-dist epilogue ----
// 1D grid 2048, XCD remap: xcd = fid&7, li = fid>>3, yg = li>>4, xi = li&15;
// column-block y = yg*8 + xcd (exit if >=125), row-block = xi.
// 2-phase pipeline: STAGE(buf^1, rnd+1) -> compute(buf) -> barrier. One
// barrier per round; gl_lds latency hides under MFMA+epilogue.
__global__ __launch_bounds__(256, 2) void decode_main(
    const u16* __restrict__ Bh_g, const u16* __restrict__ Bl_g,
    const u16* __restrict__ ahi_g, const u16* __restrict__ alo_g,
    const float* __restrict__ x2g, const float* __restrict__ y2g,
    const float* __restrict__ fbg, const float* __restrict__ tempg,
    float* __restrict__ outp)
{
  __shared__ __align__(16) u16 sBh[2*64*128];   // 32 KB (double-buffered)
  __shared__ __align__(16) u16 sBl[2*64*128];   // 32 KB
  const int fid = blockIdx.x;
  const int xcd = fid & 7, li = fid >> 3;
  const int yg  = li >> 4, xi = li & 15;
  const int ycb = yg*8 + xcd;                 // column-block 0..127
  if (ycb >= 125) return;                     // 48 pad blocks exit
  const int n_base = ycb*256;

  const int tid  = threadIdx.x;
  const int wave = tid >> 6, lane = tid & 63;
  const int l32  = lane & 31, half = lane >> 5;
  const int m0   = xi*128 + wave*32;
  const int arow = m0 + l32;

  // Persistent A fragments (act): operand layout [n=lane&31][k = ks*16+half*8+j]
  short8 ah[8], al[8];
#pragma unroll
  for (int ks = 0; ks < 8; ++ks){
    ah[ks] = *(const short8*)(ahi_g + (size_t)arow*128 + ks*16 + half*8);
    al[ks] = *(const short8*)(alo_g + (size_t)arow*128 + ks*16 + half*8);
  }
  // Per-row (per-lane) scalar precomputes
  const float xv  = x2g[arow];
  const float bb  = 1.f - xv;
  const float ntb = -2.f*bb;
  const float b2  = bb*bb;
  const float tmp = tempg[0];
  const float nit2 = -0.4804530139182014f/(tmp*tmp);  // -(ln2)^2/t^2 (log2 form)

  // staging geometry (per-thread, round-invariant)
  int s_col[4], s_swz[4], s_ldb[4];
#pragma unroll
  for (int it = 0; it < 4; ++it){
    int id = it*256 + tid;
    s_col[it] = id >> 4;
    int sg = id & 15;
    s_swz[it] = ((sg*16) ^ ((s_col[it] & 7) << 4)) >> 1;     // u16 units
    s_ldb[it] = (it*256 + (tid & ~63)) * 8;                  // wave-uniform, u16 units
  }

#define STAGE(buf, n0)                                              \
  {                                                                 \
    _Pragma("unroll")                                               \
    for (int it = 0; it < 4; ++it){                                 \
      size_t gb = (size_t)((n0) + s_col[it])*128 + s_swz[it];       \
      gl_lds16(Bh_g + gb, &sBh[(buf)*8192 + s_ldb[it]]);            \
      gl_lds16(Bl_g + gb, &sBl[(buf)*8192 + s_ldb[it]]);            \
    }                                                               \
  }

  STAGE(0, n_base);
  __syncthreads();                 // drain vmcnt -> buf0 ready

  for (int rnd = 0; rnd < 4; ++rnd){
    const int cur = rnd & 1;
    const int n0r = n_base + rnd*64;
    if (rnd < 3) STAGE(cur^1, n0r + 64);   // issue next-tile loads FIRST

#pragma unroll
    for (int ct = 0; ct < 2; ++ct){
      const int ccol = ct*32 + l32;  // code col = lane&31 (M-operand lane idx)
      f32x16 acch = {0.f,0.f,0.f,0.f,0.f,0.f,0.f,0.f,0.f,0.f,0.f,0.f,0.f,0.f,0.f,0.f};
      f32x16 accx = {0.f,0.f,0.f,0.f,0.f,0.f,0.f,0.f,0.f,0.f,0.f,0.f,0.f,0.f,0.f,0.f};
#pragma unroll
      for (int ks = 0; ks < 8; ++ks){
        int kb  = ks*32 + half*16;                           // byte within row
        int off = cur*8192 + ((ccol*256 + (kb ^ ((ccol & 7) << 4))) >> 1);
        short8 bh = *(const short8*)(&sBh[off]);
        short8 bl = *(const short8*)(&sBl[off]);
        acch = __builtin_amdgcn_mfma_f32_32x32x16_bf16(bh, ah[ks], acch, 0, 0, 0);
        accx = __builtin_amdgcn_mfma_f32_32x32x16_bf16(bl, ah[ks], accx, 0, 0, 0);
        accx = __builtin_amdgcn_mfma_f32_32x32x16_bf16(bh, al[ks], accx, 0, 0, 0);
      }
      // D: code col (reg r) = (r&3)+8*(r>>2)+4*half, act row = lane&31.
      const int cb = n0r + ct*32 + half*4;
#pragma unroll
      for (int g = 0; g < 4; ++g){
        const int cg = cb + g*8;
        const float4 y2v4 = *(const float4*)(y2g + cg);
        const float4 fbv4 = *(const float4*)(fbg + cg);
        float4 o;
#pragma unroll
        for (int q = 0; q < 4; ++q){
          const int r = g*4 + q;
          float y2v = ((const float*)&y2v4)[q];
          float t   = acch[r] + accx[r];        // xy, f32-accurate
          float two = t + t;
          float a   = (1.f + y2v) - two;        // 1 - 2xy + y2
          float den = fmaf(xv, y2v, 1.f - two);
          float dc  = fmaxf(den, 1e-15f);
          float num2 = fmaf(a*xv, a, fmaf(ntb*t, a, b2*y2v));
          float sq  = __builtin_amdgcn_sqrtf(fmaxf(num2, 0.f));
          float s   = fminf(sq, 0.99999f*dc);   // norm clip at 1-1e-5
          float lg  = __log2f(__fdividef(dc + s, dc - s)); // 2*artanh via log2
          ((float*)&o)[q] = fmaf(lg*lg, nit2, ((const float*)&fbv4)[q]);
        }
        *(float4*)(outp + (size_t)arow*32000 + cg) = o;
      }
    }
    if (rnd < 3) __syncthreads();   // drains next-tile stage; guards buf reuse
  }
#undef STAGE
}

extern "C" void kernel_launch(void* const* d_in, const int* in_sizes, int n_in,
                              void* d_out, int out_size, void* d_ws, size_t ws_size,
                              hipStream_t stream) {
  const float* vt   = (const float*)d_in[0];  // v_tangent [16,128,128]
  const float* code = (const float*)d_in[1];  // code_points [32000,128]
  const float* Wm   = (const float*)d_in[2];  // W [128,128]
  const float* bias = (const float*)d_in[3];  // b [128]
  const float* fb   = (const float*)d_in[4];  // freq_bias [32000]
  const float* temp = (const float*)d_in[5];  // temperature [1]
  float* outp = (float*)d_out;

  char* ws = (char*)d_ws;
  u16*   ahi = (u16*)ws;                            // 512 KB
  u16*   alo = (u16*)(ws + 512*1024);               // 512 KB
  float* x2  = (float*)(ws + 1024*1024);            // 8 KB
  float* y2  = (float*)(ws + 1024*1024 + 8192);     // 128 KB
  u16*   Bh  = (u16*)(ws + 1280*1024);              // 8.192 MB
  u16*   Bl  = (u16*)(ws + 1280*1024 + 8192*1024);  // 8.192 MB

  prep_kernel<<<2048, 64, 0, stream>>>(vt, Wm, bias, ahi, alo, x2);
  split_y2_kernel<<<4000, 256, 0, stream>>>(code, Bh, Bl, y2);
  decode_main<<<2048, 256, 0, stream>>>(Bh, Bl, ahi, alo, x2, y2, fb, temp, outp);
}